// Round 2
// baseline (462.264 us; speedup 1.0000x reference)
//
#include <hip/hip_runtime.h>

// MyGNN on MI355X. All float tensors are float32 (per reference), ints int32,
// output float32 of shape [2, M, 128] flattened.
//
// Pipeline:
//   fill_buckets: edge list -> per-dst bucket CSR (CAP=64 slots/node)
//   aggregate:    one wave per dst node, register accumulate of src rows
//   gemm128:      [rows,128] @ W[128,128] + b, W staged in 64KB LDS,
//                 optional 2-D gather of input rows

#define B_    64
#define ADJ_  1000
#define N_    64000      // B_*ADJ_
#define E_    (1 << 20)
#define M_    32000
#define DV    128
#define CAP   64         // max in-degree capacity (Poisson(16.4), max ~ 40)

// ---------------- bucket CSR build ----------------
__global__ __launch_bounds__(256)
void fill_buckets(const int* __restrict__ ei, int* __restrict__ counts,
                  int* __restrict__ bucket) {
  int e = blockIdx.x * 256 + threadIdx.x;
  int src = ei[e];
  int dst = ei[E_ + e];
  int pos = atomicAdd(&counts[dst], 1);
  if (pos < CAP) bucket[dst * CAP + pos] = src;   // overflow impossible for this input
}

// ---------------- aggregation: one wave per dst node ----------------
// out[n,:] = sum_{e: dst(e)=n} x[src(e), :]    (f32 in, f32 out)
__global__ __launch_bounds__(256)
void aggregate(const float* __restrict__ x, const int* __restrict__ counts,
               const int* __restrict__ bucket, float* __restrict__ out) {
  int w    = (blockIdx.x * 256 + threadIdx.x) >> 6;   // node id
  int lane = threadIdx.x & 63;
  if (w >= N_) return;
  int cnt = counts[w]; cnt = min(cnt, CAP);
  int mysrc = bucket[w * CAP + lane];                 // lanes >= cnt unused
  float2 acc; acc.x = 0.f; acc.y = 0.f;
  const float2* x2 = (const float2*)x;

  int d = 0;
  for (; d + 4 <= cnt; d += 4) {
    int s0 = __shfl(mysrc, d, 64);
    int s1 = __shfl(mysrc, d + 1, 64);
    int s2 = __shfl(mysrc, d + 2, 64);
    int s3 = __shfl(mysrc, d + 3, 64);
    float2 v0 = x2[(size_t)s0 * 64 + lane];
    float2 v1 = x2[(size_t)s1 * 64 + lane];
    float2 v2 = x2[(size_t)s2 * 64 + lane];
    float2 v3 = x2[(size_t)s3 * 64 + lane];
    acc.x += (v0.x + v1.x) + (v2.x + v3.x);
    acc.y += (v0.y + v1.y) + (v2.y + v3.y);
  }
  for (; d < cnt; d++) {
    int s = __shfl(mysrc, d, 64);
    float2 v = x2[(size_t)s * 64 + lane];
    acc.x += v.x; acc.y += v.y;
  }
  ((float2*)out)[(size_t)w * 64 + lane] = acc;
}

// ---------------- GEMM: out[r,:] = row(in, r) @ W[128,128] + bias ----------------
// 256 threads: tx = tid&7 -> 16-col group, ty = tid>>3 -> rows ty, ty+32 of a
// 64-row tile. W (f32, 64KB) staged in LDS. rows % 64 == 0.
template<bool GATHER>
__global__ __launch_bounds__(256)
void gemm128(const float* __restrict__ in, const float* __restrict__ W,
             const float* __restrict__ bias, float* __restrict__ out,
             int rows, const int* __restrict__ bidx, const int* __restrict__ nidx) {
  __shared__ float Ws[DV * DV];      // 65536 bytes
  int tid = threadIdx.x;
  {
    const float4* W4 = (const float4*)W;
    float4* S4 = (float4*)Ws;
#pragma unroll
    for (int i = 0; i < 16; i++) S4[tid + i * 256] = W4[tid + i * 256];
  }
  __syncthreads();

  int tx = tid & 7;          // col group: cols tx*16 .. tx*16+15
  int ty = tid >> 3;         // 0..31
  int cbase = tx * 16;

  float bv[16];
#pragma unroll
  for (int c = 0; c < 16; c++) bv[c] = bias[cbase + c];

  for (int base = blockIdx.x * 64; base < rows; base += gridDim.x * 64) {
    int r0 = base + ty, r1 = r0 + 32;
    size_t ir0, ir1;
    if (GATHER) {
      ir0 = (size_t)bidx[r0] * ADJ_ + nidx[r0];
      ir1 = (size_t)bidx[r1] * ADJ_ + nidx[r1];
    } else {
      ir0 = (size_t)r0; ir1 = (size_t)r1;
    }

    float acc0[16], acc1[16];
#pragma unroll
    for (int c = 0; c < 16; c++) { acc0[c] = 0.f; acc1[c] = 0.f; }

    const float4* a0 = (const float4*)(in + ir0 * DV);
    const float4* a1 = (const float4*)(in + ir1 * DV);

#pragma unroll 4
    for (int kb = 0; kb < 32; kb++) {
      float4 t0 = a0[kb], t1 = a1[kb];
      float a0v[4] = {t0.x, t0.y, t0.z, t0.w};
      float a1v[4] = {t1.x, t1.y, t1.z, t1.w};
#pragma unroll
      for (int j = 0; j < 4; j++) {
        const float4* wr = (const float4*)(Ws + (kb * 4 + j) * DV + cbase);
        float4 w0 = wr[0], w1 = wr[1], w2 = wr[2], w3 = wr[3];
        float aj0 = a0v[j], aj1 = a1v[j];
#define FMA16(ACC, AJ)                                                         \
        ACC[0]  += AJ * w0.x; ACC[1]  += AJ * w0.y; ACC[2]  += AJ * w0.z; ACC[3]  += AJ * w0.w; \
        ACC[4]  += AJ * w1.x; ACC[5]  += AJ * w1.y; ACC[6]  += AJ * w1.z; ACC[7]  += AJ * w1.w; \
        ACC[8]  += AJ * w2.x; ACC[9]  += AJ * w2.y; ACC[10] += AJ * w2.z; ACC[11] += AJ * w2.w; \
        ACC[12] += AJ * w3.x; ACC[13] += AJ * w3.y; ACC[14] += AJ * w3.z; ACC[15] += AJ * w3.w;
        FMA16(acc0, aj0)
        FMA16(acc1, aj1)
#undef FMA16
      }
    }

    float4* p = (float4*)(out + (size_t)r0 * DV + cbase);
    float4* q = (float4*)(out + (size_t)r1 * DV + cbase);
#pragma unroll
    for (int g = 0; g < 4; g++) {
      p[g] = make_float4(acc0[g*4+0] + bv[g*4+0], acc0[g*4+1] + bv[g*4+1],
                         acc0[g*4+2] + bv[g*4+2], acc0[g*4+3] + bv[g*4+3]);
      q[g] = make_float4(acc1[g*4+0] + bv[g*4+0], acc1[g*4+1] + bv[g*4+1],
                         acc1[g*4+2] + bv[g*4+2], acc1[g*4+3] + bv[g*4+3]);
    }
  }
}

extern "C" void kernel_launch(void* const* d_in, const int* in_sizes, int n_in,
                              void* d_out, int out_size, void* d_ws, size_t ws_size,
                              hipStream_t stream) {
  const float* x0  = (const float*)d_in[0];
  const float* x1  = (const float*)d_in[1];
  const int*   ei  = (const int*)  d_in[2];
  const int*   b0  = (const int*)  d_in[3];
  const int*   n0i = (const int*)  d_in[4];
  const int*   b1  = (const int*)  d_in[5];
  const int*   n1i = (const int*)  d_in[6];
  const float* W1  = (const float*)d_in[7];
  const float* bb1 = (const float*)d_in[8];
  const float* W2  = (const float*)d_in[9];
  const float* bb2 = (const float*)d_in[10];
  const float* Wl  = (const float*)d_in[11];
  const float* bl  = (const float*)d_in[12];
  const float* Wfi = (const float*)d_in[13];
  const float* bfi = (const float*)d_in[14];
  float* out = (float*)d_out;

  // workspace: bufA (32MB f32) | bufB (32MB f32) | counts (256KB) | bucket (16MB)
  float* bufA   = (float*)d_ws;
  float* bufB   = bufA + (size_t)N_ * DV;
  int*   counts = (int*)(bufB + (size_t)N_ * DV);
  int*   bucket = counts + N_;

  hipMemsetAsync(counts, 0, N_ * sizeof(int), stream);
  fill_buckets<<<E_ / 256, 256, 0, stream>>>(ei, counts, bucket);

  // layer 1: agg1 = A @ x1 -> bufA ; h1 = agg1@W1+b1 -> bufB
  aggregate<<<N_ / 4, 256, 0, stream>>>(x1, counts, bucket, bufA);
  gemm128<false><<<N_ / 64, 256, 0, stream>>>(bufA, W1, bb1, bufB, N_, nullptr, nullptr);

  // layer 2: agg2 = A @ h1 -> bufA ; h2 = agg2@W2+b2 -> bufB
  aggregate<<<N_ / 4, 256, 0, stream>>>(bufB, counts, bucket, bufA);
  gemm128<false><<<N_ / 64, 256, 0, stream>>>(bufA, W2, bb2, bufB, N_, nullptr, nullptr);

  // branch 0: d0 = gather(x0)[M] @ Wfi + bfi -> out[0 : M*128]
  gemm128<true><<<M_ / 64, 256, 0, stream>>>(x0, Wfi, bfi, out, M_, b0, n0i);

  // branch 1: d1 = gather(h2)[M] @ Wl + bl -> out[M*128 : 2*M*128]
  gemm128<true><<<M_ / 64, 256, 0, stream>>>(bufB, Wl, bl, out + (size_t)M_ * DV, M_, b1, n1i);
}

// Round 3
// 386.943 us; speedup vs baseline: 1.1947x; 1.1947x over previous
//
#include <hip/hip_runtime.h>

// MyGNN on MI355X — round 3.
// Reorder via linearity: h = (A@x)@W + b  ==  A@(x@W) + b.
//   gemm (f32 in, bf16 out, no bias) -> aggregate (bf16 in, +bias, f32 out)
// fill_buckets sharded by dst-range for L2 write-combining; bucket = ushort.

#define B_    64
#define ADJ_  1000
#define N_    64000      // B_*ADJ_
#define E_    (1 << 20)
#define M_    32000
#define DV    128
#define CAP   64         // max in-degree (Poisson(16.4), max ~ 45)
#define RANGES 8
#define RSPAN  (N_ / RANGES)   // 8000
#define CHUNKS 512
#define EPB    (E_ / CHUNKS)   // 2048 edges per chunk

typedef __attribute__((ext_vector_type(8))) unsigned short ushort8v;

__device__ __forceinline__ float u2f(unsigned int u) {
  union { unsigned int i; float f; } x; x.i = u; return x.f;
}
__device__ __forceinline__ unsigned short f2bf(float f) {   // RNE
  union { float f; unsigned int i; } x; x.f = f;
  unsigned int r = x.i + 0x7fffu + ((x.i >> 16) & 1u);
  return (unsigned short)(r >> 16);
}

// ---------------- bucket CSR build, dst-range sharded ----------------
// blockIdx%8 -> dst range (8000 nodes, 1MB bucket shard); consecutive blockIdx
// round-robin across XCDs, so each shard's writes combine in one L2.
// Correct for ANY blockIdx->XCD mapping (every edge seen by exactly one
// (chunk,range) owner per range membership).
__global__ __launch_bounds__(256)
void fill_buckets(const int* __restrict__ ei, int* __restrict__ counts,
                  unsigned short* __restrict__ bucket) {
  int r  = blockIdx.x & (RANGES - 1);
  int c  = blockIdx.x >> 3;
  int lo = r * RSPAN, hi = lo + RSPAN;
  int base = c * EPB;
#pragma unroll
  for (int i = 0; i < EPB / 256; i++) {
    int e = base + i * 256 + threadIdx.x;
    int dst = ei[E_ + e];
    if (dst >= lo && dst < hi) {
      int src = ei[e];
      int pos = atomicAdd(&counts[dst], 1);
      if (pos < CAP) bucket[dst * CAP + pos] = (unsigned short)src;
    }
  }
}

// ---------------- aggregation: one wave per dst node ----------------
// out[n,:] = bias[:] + sum_{e: dst(e)=n} x[src(e), :]   (bf16 in, f32 out)
__global__ __launch_bounds__(256)
void aggregate_bf16(const unsigned int* __restrict__ x,   // bf16x2 rows [N,64]
                    const int* __restrict__ counts,
                    const unsigned short* __restrict__ bucket,
                    const float* __restrict__ bias,
                    float* __restrict__ out) {
  int w    = (blockIdx.x * 256 + threadIdx.x) >> 6;
  int lane = threadIdx.x & 63;
  if (w >= N_) return;
  int cnt = counts[w]; cnt = min(cnt, CAP);
  int mysrc = (int)bucket[w * CAP + lane];            // lanes >= cnt unused
  float2 acc; acc.x = bias[lane * 2]; acc.y = bias[lane * 2 + 1];

  int d = 0;
  for (; d + 4 <= cnt; d += 4) {
    int s0 = __shfl(mysrc, d, 64);
    int s1 = __shfl(mysrc, d + 1, 64);
    int s2 = __shfl(mysrc, d + 2, 64);
    int s3 = __shfl(mysrc, d + 3, 64);
    unsigned int u0 = x[(size_t)s0 * 64 + lane];
    unsigned int u1 = x[(size_t)s1 * 64 + lane];
    unsigned int u2 = x[(size_t)s2 * 64 + lane];
    unsigned int u3 = x[(size_t)s3 * 64 + lane];
    acc.x += (u2f(u0 << 16) + u2f(u1 << 16)) + (u2f(u2 << 16) + u2f(u3 << 16));
    acc.y += (u2f(u0 & 0xffff0000u) + u2f(u1 & 0xffff0000u))
           + (u2f(u2 & 0xffff0000u) + u2f(u3 & 0xffff0000u));
  }
  for (; d < cnt; d++) {
    int s = __shfl(mysrc, d, 64);
    unsigned int u = x[(size_t)s * 64 + lane];
    acc.x += u2f(u << 16);
    acc.y += u2f(u & 0xffff0000u);
  }
  ((float2*)out)[(size_t)w * 64 + lane] = acc;
}

// ---------------- GEMM: out[r,:] = row(in, r) @ W[128,128] (+ bias) ----------------
// 256 threads: tx = tid&7 -> 16-col group, ty = tid>>3 -> rows ty, ty+32 of a
// 64-row tile. W (f32, 64KB) staged in LDS. rows % 64 == 0.
template<bool GATHER, bool OUTBF16, bool HASBIAS>
__global__ __launch_bounds__(256)
void gemm128(const float* __restrict__ in, const float* __restrict__ W,
             const float* __restrict__ bias, void* __restrict__ out_,
             int rows, const int* __restrict__ bidx, const int* __restrict__ nidx) {
  __shared__ float Ws[DV * DV];      // 65536 bytes
  int tid = threadIdx.x;
  {
    const float4* W4 = (const float4*)W;
    float4* S4 = (float4*)Ws;
#pragma unroll
    for (int i = 0; i < 16; i++) S4[tid + i * 256] = W4[tid + i * 256];
  }
  __syncthreads();

  int tx = tid & 7;
  int ty = tid >> 3;
  int cbase = tx * 16;

  float bv[16];
#pragma unroll
  for (int c = 0; c < 16; c++) bv[c] = HASBIAS ? bias[cbase + c] : 0.f;

  for (int base = blockIdx.x * 64; base < rows; base += gridDim.x * 64) {
    int r0 = base + ty, r1 = r0 + 32;
    size_t ir0, ir1;
    if (GATHER) {
      ir0 = (size_t)bidx[r0] * ADJ_ + nidx[r0];
      ir1 = (size_t)bidx[r1] * ADJ_ + nidx[r1];
    } else {
      ir0 = (size_t)r0; ir1 = (size_t)r1;
    }

    float acc0[16], acc1[16];
#pragma unroll
    for (int c = 0; c < 16; c++) { acc0[c] = 0.f; acc1[c] = 0.f; }

    const float4* a0 = (const float4*)(in + ir0 * DV);
    const float4* a1 = (const float4*)(in + ir1 * DV);

#pragma unroll 4
    for (int kb = 0; kb < 32; kb++) {
      float4 t0 = a0[kb], t1 = a1[kb];
      float a0v[4] = {t0.x, t0.y, t0.z, t0.w};
      float a1v[4] = {t1.x, t1.y, t1.z, t1.w};
#pragma unroll
      for (int j = 0; j < 4; j++) {
        const float4* wr = (const float4*)(Ws + (kb * 4 + j) * DV + cbase);
        float4 w0 = wr[0], w1 = wr[1], w2 = wr[2], w3 = wr[3];
        float aj0 = a0v[j], aj1 = a1v[j];
#define FMA16(ACC, AJ)                                                         \
        ACC[0]  += AJ * w0.x; ACC[1]  += AJ * w0.y; ACC[2]  += AJ * w0.z; ACC[3]  += AJ * w0.w; \
        ACC[4]  += AJ * w1.x; ACC[5]  += AJ * w1.y; ACC[6]  += AJ * w1.z; ACC[7]  += AJ * w1.w; \
        ACC[8]  += AJ * w2.x; ACC[9]  += AJ * w2.y; ACC[10] += AJ * w2.z; ACC[11] += AJ * w2.w; \
        ACC[12] += AJ * w3.x; ACC[13] += AJ * w3.y; ACC[14] += AJ * w3.z; ACC[15] += AJ * w3.w;
        FMA16(acc0, aj0)
        FMA16(acc1, aj1)
#undef FMA16
      }
    }

    if (OUTBF16) {
      unsigned short st0[16], st1[16];
#pragma unroll
      for (int c = 0; c < 16; c++) {
        st0[c] = f2bf(acc0[c] + bv[c]);
        st1[c] = f2bf(acc1[c] + bv[c]);
      }
      unsigned short* o = (unsigned short*)out_;
      ushort8v* p = (ushort8v*)(o + (size_t)r0 * DV + cbase);
      p[0] = *(const ushort8v*)&st0[0];
      p[1] = *(const ushort8v*)&st0[8];
      ushort8v* q = (ushort8v*)(o + (size_t)r1 * DV + cbase);
      q[0] = *(const ushort8v*)&st1[0];
      q[1] = *(const ushort8v*)&st1[8];
    } else {
      float* o = (float*)out_;
      float4* p = (float4*)(o + (size_t)r0 * DV + cbase);
      float4* q = (float4*)(o + (size_t)r1 * DV + cbase);
#pragma unroll
      for (int g = 0; g < 4; g++) {
        p[g] = make_float4(acc0[g*4+0] + bv[g*4+0], acc0[g*4+1] + bv[g*4+1],
                           acc0[g*4+2] + bv[g*4+2], acc0[g*4+3] + bv[g*4+3]);
        q[g] = make_float4(acc1[g*4+0] + bv[g*4+0], acc1[g*4+1] + bv[g*4+1],
                           acc1[g*4+2] + bv[g*4+2], acc1[g*4+3] + bv[g*4+3]);
      }
    }
  }
}

extern "C" void kernel_launch(void* const* d_in, const int* in_sizes, int n_in,
                              void* d_out, int out_size, void* d_ws, size_t ws_size,
                              hipStream_t stream) {
  const float* x0  = (const float*)d_in[0];
  const float* x1  = (const float*)d_in[1];
  const int*   ei  = (const int*)  d_in[2];
  const int*   b0  = (const int*)  d_in[3];
  const int*   n0i = (const int*)  d_in[4];
  const int*   b1  = (const int*)  d_in[5];
  const int*   n1i = (const int*)  d_in[6];
  const float* W1  = (const float*)d_in[7];
  const float* bb1 = (const float*)d_in[8];
  const float* W2  = (const float*)d_in[9];
  const float* bb2 = (const float*)d_in[10];
  const float* Wl  = (const float*)d_in[11];
  const float* bl  = (const float*)d_in[12];
  const float* Wfi = (const float*)d_in[13];
  const float* bfi = (const float*)d_in[14];
  float* out = (float*)d_out;

  // workspace: t_bf (16MB bf16) | h (32MB f32) | counts (256KB) | bucket16 (8MB)
  unsigned int*   t_bf   = (unsigned int*)d_ws;                 // [N,64] bf16x2
  float*          h      = (float*)(t_bf + (size_t)N_ * 64);
  int*            counts = (int*)(h + (size_t)N_ * DV);
  unsigned short* bucket = (unsigned short*)(counts + N_);

  hipMemsetAsync(counts, 0, N_ * sizeof(int), stream);
  fill_buckets<<<CHUNKS * RANGES, 256, 0, stream>>>(ei, counts, bucket);

  // layer 1: t1 = x1@W1 (bf16) ; h1 = A@t1 + b1 (f32)
  gemm128<false, true, false><<<N_ / 64, 256, 0, stream>>>(x1, W1, nullptr, t_bf, N_, nullptr, nullptr);
  aggregate_bf16<<<N_ / 4, 256, 0, stream>>>(t_bf, counts, bucket, bb1, h);

  // layer 2: t2 = h1@W2 (bf16) ; h2 = A@t2 + b2 (f32, reuses h)
  gemm128<false, true, false><<<N_ / 64, 256, 0, stream>>>(h, W2, nullptr, t_bf, N_, nullptr, nullptr);
  aggregate_bf16<<<N_ / 4, 256, 0, stream>>>(t_bf, counts, bucket, bb2, h);

  // branch 0: d0 = gather(x0)[M] @ Wfi + bfi
  gemm128<true, false, true><<<M_ / 64, 256, 0, stream>>>(x0, Wfi, bfi, out, M_, b0, n0i);

  // branch 1: d1 = gather(h2)[M] @ Wl + bl
  gemm128<true, false, true><<<M_ / 64, 256, 0, stream>>>(h, Wl, bl, out + (size_t)M_ * DV, M_, b1, n1i);
}

// Round 4
// 293.242 us; speedup vs baseline: 1.5764x; 1.3195x over previous
//
#include <hip/hip_runtime.h>
#include <hip/hip_bf16.h>

// MyGNN on MI355X — round 4.
// GEMMs now use mfma_f32_16x16x32_bf16 (fp32 accumulate, bf16-rounded inputs).
// Structure: h = A@(x@W) + b (linearity reorder); bucket-CSR aggregation.

#define B_    64
#define ADJ_  1000
#define N_    64000      // B_*ADJ_
#define E_    (1 << 20)
#define M_    32000
#define DV    128
#define CAP   64         // max in-degree (Poisson(16.4), max ~ 45)
#define RANGES 8
#define RSPAN  (N_ / RANGES)   // 8000
#define CHUNKS 512
#define EPB    (E_ / CHUNKS)   // 2048 edges per chunk

typedef __attribute__((ext_vector_type(8))) short short8v;   // 8 bf16 (4 VGPRs)
typedef __attribute__((ext_vector_type(4))) float float4v;   // MFMA acc

__device__ __forceinline__ float u2f(unsigned int u) {
  union { unsigned int i; float f; } x; x.i = u; return x.f;
}
__device__ __forceinline__ unsigned short f2bf(float f) {   // RNE
  union { float f; unsigned int i; } x; x.f = f;
  unsigned int r = x.i + 0x7fffu + ((x.i >> 16) & 1u);
  return (unsigned short)(r >> 16);
}
__device__ __forceinline__ unsigned int pack_bf2(float a, float b) {  // v_cvt_pk_bf16_f32
  __hip_bfloat162 h = __float22bfloat162_rn(float2{a, b});
  union { __hip_bfloat162 h; unsigned int u; } c; c.h = h;
  return c.u;
}

// ---------------- bucket CSR build, dst-range sharded ----------------
__global__ __launch_bounds__(256)
void fill_buckets(const int* __restrict__ ei, int* __restrict__ counts,
                  unsigned short* __restrict__ bucket) {
  int r  = blockIdx.x & (RANGES - 1);
  int c  = blockIdx.x >> 3;
  int lo = r * RSPAN, hi = lo + RSPAN;
  int base = c * EPB;
#pragma unroll
  for (int i = 0; i < EPB / 256; i++) {
    int e = base + i * 256 + threadIdx.x;
    int dst = ei[E_ + e];
    if (dst >= lo && dst < hi) {
      int src = ei[e];
      int pos = atomicAdd(&counts[dst], 1);
      if (pos < CAP) bucket[dst * CAP + pos] = (unsigned short)src;
    }
  }
}

// ---------------- aggregation: one wave per dst node ----------------
// out[n,:] = bias[:] + sum_{e: dst(e)=n} x[src(e), :]   (bf16 in, f32 out)
__global__ __launch_bounds__(256)
void aggregate_bf16(const unsigned int* __restrict__ x,   // bf16x2 rows [N,64]
                    const int* __restrict__ counts,
                    const unsigned short* __restrict__ bucket,
                    const float* __restrict__ bias,
                    float* __restrict__ out) {
  int w    = (blockIdx.x * 256 + threadIdx.x) >> 6;
  int lane = threadIdx.x & 63;
  if (w >= N_) return;
  int cnt = counts[w]; cnt = min(cnt, CAP);
  int mysrc = (int)bucket[w * CAP + lane];
  float2 acc; acc.x = bias[lane * 2]; acc.y = bias[lane * 2 + 1];

  int d = 0;
  for (; d + 4 <= cnt; d += 4) {
    int s0 = __shfl(mysrc, d, 64);
    int s1 = __shfl(mysrc, d + 1, 64);
    int s2 = __shfl(mysrc, d + 2, 64);
    int s3 = __shfl(mysrc, d + 3, 64);
    unsigned int u0 = x[(size_t)s0 * 64 + lane];
    unsigned int u1 = x[(size_t)s1 * 64 + lane];
    unsigned int u2 = x[(size_t)s2 * 64 + lane];
    unsigned int u3 = x[(size_t)s3 * 64 + lane];
    acc.x += (u2f(u0 << 16) + u2f(u1 << 16)) + (u2f(u2 << 16) + u2f(u3 << 16));
    acc.y += (u2f(u0 & 0xffff0000u) + u2f(u1 & 0xffff0000u))
           + (u2f(u2 & 0xffff0000u) + u2f(u3 & 0xffff0000u));
  }
  for (; d < cnt; d++) {
    int s = __shfl(mysrc, d, 64);
    unsigned int u = x[(size_t)s * 64 + lane];
    acc.x += u2f(u << 16);
    acc.y += u2f(u & 0xffff0000u);
  }
  ((float2*)out)[(size_t)w * 64 + lane] = acc;
}

// ---------------- MFMA GEMM: out[r,:] = row(in,r) @ W[128,128] (+bias) ----------
// Block 256 = 4 waves; block tile = 64 rows; wave stripe = 16 rows x 128 cols.
// W converted f32->bf16 into LDS in exact B-fragment order:
//   frag(nb,kc,lane) j=0..7  =  W[kc*32 + (lane>>4)*8 + j][nb*16 + (lane&15)]
// A-frag built from global f32 (2x dwordx4 + cvt_pk): A[m=lane&15][k=q*8+j].
// C/D: col = lane&15, row = (lane>>4)*4 + reg   (m89-verified).
template<bool GATHER, bool OUTBF16, bool HASBIAS>
__global__ __launch_bounds__(256)
void gemm_mfma(const float* __restrict__ in, const float* __restrict__ W,
               const float* __restrict__ bias, void* __restrict__ out_,
               const int* __restrict__ bidx, const int* __restrict__ nidx) {
  __shared__ unsigned short Bs[8 * 4 * 64 * 8];   // 32 KB, frag-ordered bf16
  int tid = threadIdx.x;

  // stage W: coalesced f32 read, scattered 2B LDS write (one-time)
#pragma unroll 8
  for (int i = 0; i < 64; i++) {
    int g = i * 256 + tid;            // 0..16383
    int k = g >> 7, n = g & 127;
    int addr = ((((n >> 4) * 4 + (k >> 5)) * 64 + ((k >> 3) & 3) * 16 + (n & 15)) << 3)
             + (k & 7);
    Bs[addr] = f2bf(W[g]);
  }
  __syncthreads();

  int lane = tid & 63;
  int wv   = tid >> 6;
  int m    = lane & 15;
  int q    = lane >> 4;
  int rbase = blockIdx.x * 64 + wv * 16;
  int r     = rbase + m;

  size_t ir;
  if (GATHER) ir = (size_t)bidx[r] * ADJ_ + nidx[r];
  else        ir = (size_t)r;
  const float* arow = in + ir * DV;

  // build 4 A-frags (k-chunks of 32; this lane covers k = kc*32 + q*8 .. +7)
  short8v af[4];
#pragma unroll
  for (int kc = 0; kc < 4; kc++) {
    const float4* p = (const float4*)(arow + kc * 32 + q * 8);
    float4 f0 = p[0], f1 = p[1];
    union { short8v s; unsigned int u[4]; } t;
    t.u[0] = pack_bf2(f0.x, f0.y);
    t.u[1] = pack_bf2(f0.z, f0.w);
    t.u[2] = pack_bf2(f1.x, f1.y);
    t.u[3] = pack_bf2(f1.z, f1.w);
    af[kc] = t.s;
  }

  float4v acc[8];
#pragma unroll
  for (int nb = 0; nb < 8; nb++) acc[nb] = (float4v){0.f, 0.f, 0.f, 0.f};

#pragma unroll
  for (int nb = 0; nb < 8; nb++) {
#pragma unroll
    for (int kc = 0; kc < 4; kc++) {
      short8v bf = *(const short8v*)(Bs + (((nb * 4 + kc) * 64 + lane) << 3));
      acc[nb] = __builtin_amdgcn_mfma_f32_16x16x32_bf16(af[kc], bf, acc[nb], 0, 0, 0);
    }
  }

  // epilogue: D row = q*4+i, col = nb*16+m
#pragma unroll
  for (int nb = 0; nb < 8; nb++) {
    float bvn = HASBIAS ? bias[nb * 16 + m] : 0.f;
    int col = nb * 16 + m;
#pragma unroll
    for (int i = 0; i < 4; i++) {
      int row = rbase + q * 4 + i;
      float v = acc[nb][i] + bvn;
      if (OUTBF16) ((unsigned short*)out_)[(size_t)row * DV + col] = f2bf(v);
      else         ((float*)out_)[(size_t)row * DV + col] = v;
    }
  }
}

extern "C" void kernel_launch(void* const* d_in, const int* in_sizes, int n_in,
                              void* d_out, int out_size, void* d_ws, size_t ws_size,
                              hipStream_t stream) {
  const float* x0  = (const float*)d_in[0];
  const float* x1  = (const float*)d_in[1];
  const int*   ei  = (const int*)  d_in[2];
  const int*   b0  = (const int*)  d_in[3];
  const int*   n0i = (const int*)  d_in[4];
  const int*   b1  = (const int*)  d_in[5];
  const int*   n1i = (const int*)  d_in[6];
  const float* W1  = (const float*)d_in[7];
  const float* bb1 = (const float*)d_in[8];
  const float* W2  = (const float*)d_in[9];
  const float* bb2 = (const float*)d_in[10];
  const float* Wl  = (const float*)d_in[11];
  const float* bl  = (const float*)d_in[12];
  const float* Wfi = (const float*)d_in[13];
  const float* bfi = (const float*)d_in[14];
  float* out = (float*)d_out;

  // workspace: t_bf (16MB bf16) | h (32MB f32) | counts (256KB) | bucket16 (8MB)
  unsigned int*   t_bf   = (unsigned int*)d_ws;                 // [N,64] bf16x2
  float*          h      = (float*)(t_bf + (size_t)N_ * 64);
  int*            counts = (int*)(h + (size_t)N_ * DV);
  unsigned short* bucket = (unsigned short*)(counts + N_);

  hipMemsetAsync(counts, 0, N_ * sizeof(int), stream);
  fill_buckets<<<CHUNKS * RANGES, 256, 0, stream>>>(ei, counts, bucket);

  // layer 1: t1 = x1@W1 (bf16) ; h1 = A@t1 + b1 (f32)
  gemm_mfma<false, true, false><<<N_ / 64, 256, 0, stream>>>(x1, W1, nullptr, t_bf, nullptr, nullptr);
  aggregate_bf16<<<N_ / 4, 256, 0, stream>>>(t_bf, counts, bucket, bb1, h);

  // layer 2: t2 = h1@W2 (bf16) ; h2 = A@t2 + b2 (f32)
  gemm_mfma<false, true, false><<<N_ / 64, 256, 0, stream>>>(h, W2, nullptr, t_bf, nullptr, nullptr);
  aggregate_bf16<<<N_ / 4, 256, 0, stream>>>(t_bf, counts, bucket, bb2, h);

  // branch 0: d0 = gather(x0)[M] @ Wfi + bfi
  gemm_mfma<true, false, true><<<M_ / 64, 256, 0, stream>>>(x0, Wfi, bfi, out, b0, n0i);

  // branch 1: d1 = gather(h2)[M] @ Wl + bl
  gemm_mfma<true, false, true><<<M_ / 64, 256, 0, stream>>>(h, Wl, bl, out + (size_t)M_ * DV, b1, n1i);
}

// Round 5
// 269.465 us; speedup vs baseline: 1.7155x; 1.0882x over previous
//
#include <hip/hip_runtime.h>
#include <hip/hip_bf16.h>

// MyGNN on MI355X — round 5.
//  K1 (fused): fill_buckets ∪ gemm1(x1@W1->t_bf) ∪ branch0(gather x0 @Wfi -> out)
//  agg1: h1 = A@t1 + b1 (bf16 out)
//  gemm2: t2 = h1@W2 (bf16 out)
//  agg2_sel: sel[m] = b2 + A-row(node(m)) @ t2   (only M selected rows, bf16 out)
//  br1: out1 = sel@Wl + bl
// All GEMMs: mfma_f32_16x16x32_bf16, fp32 accumulate.

#define B_    64
#define ADJ_  1000
#define N_    64000
#define E_    (1 << 20)
#define M_    32000
#define DV    128
#define CAP   64
#define RANGES 8
#define RSPAN  (N_ / RANGES)   // 8000
#define CHUNKS 512
#define EPB    (E_ / CHUNKS)   // 2048

typedef __attribute__((ext_vector_type(8))) short short8v;   // 8 bf16
typedef __attribute__((ext_vector_type(4))) float float4v;

__device__ __forceinline__ float u2f(unsigned int u) {
  union { unsigned int i; float f; } x; x.i = u; return x.f;
}
__device__ __forceinline__ unsigned short f2bf(float f) {   // RNE
  union { float f; unsigned int i; } x; x.f = f;
  unsigned int r = x.i + 0x7fffu + ((x.i >> 16) & 1u);
  return (unsigned short)(r >> 16);
}
__device__ __forceinline__ unsigned int pack_bf2(float a, float b) {
  __hip_bfloat162 h = __float22bfloat162_rn(float2{a, b});
  union { __hip_bfloat162 h; unsigned int u; } c; c.h = h;
  return c.u;
}

// ---------------- fill part (device fn): chunk c, dst-range r ----------------
__device__ __forceinline__ void fill_part(const int* __restrict__ ei,
                                          int* __restrict__ counts,
                                          unsigned short* __restrict__ bucket,
                                          int c, int r) {
  const int* srcA = ei;
  const int* dstA = ei + E_;
  int lo = r * RSPAN;
  int t4 = c * EPB + (int)threadIdx.x * 4;
  int4 d0 = *(const int4*)(dstA + t4);
  int4 s0 = *(const int4*)(srcA + t4);
  int4 d1 = *(const int4*)(dstA + t4 + 1024);
  int4 s1 = *(const int4*)(srcA + t4 + 1024);
#define PROC(D, S) do {                                                \
    if ((unsigned)((D) - lo) < (unsigned)RSPAN) {                      \
      int pos = atomicAdd(&counts[(D)], 1);                            \
      if (pos < CAP) bucket[(D) * CAP + pos] = (unsigned short)(S);    \
    } } while (0)
  PROC(d0.x, s0.x); PROC(d0.y, s0.y); PROC(d0.z, s0.z); PROC(d0.w, s0.w);
  PROC(d1.x, s1.x); PROC(d1.y, s1.y); PROC(d1.z, s1.z); PROC(d1.w, s1.w);
#undef PROC
}

// ---------------- MFMA GEMM tile (device fn) ----------------
// tile = 64 rows; 4 waves x 16-row stripes; W f32->bf16 staged frag-ordered in LDS.
// B-frag(nb,kc,lane)[j] = W[kc*32 + (lane>>4)*8 + j][nb*16 + (lane&15)]
// C/D: col = lane&15, row = (lane>>4)*4 + reg.
template<bool GATHER, bool ABF16, bool OUTBF16, bool HASBIAS>
__device__ __forceinline__ void gemm_tile(const void* __restrict__ in,
                                          const float* __restrict__ W,
                                          const float* __restrict__ bias,
                                          void* __restrict__ out_, int tile,
                                          const int* __restrict__ bidx,
                                          const int* __restrict__ nidx,
                                          unsigned short* __restrict__ Bs) {
  int tid = threadIdx.x;
#pragma unroll 8
  for (int i = 0; i < 64; i++) {
    int g = i * 256 + tid;
    int k = g >> 7, n = g & 127;
    int addr = ((((n >> 4) * 4 + (k >> 5)) * 64 + ((k >> 3) & 3) * 16 + (n & 15)) << 3)
             + (k & 7);
    Bs[addr] = f2bf(W[g]);
  }
  __syncthreads();

  int lane = tid & 63;
  int wv   = tid >> 6;
  int m    = lane & 15;
  int q    = lane >> 4;
  int rbase = tile * 64 + wv * 16;
  int r     = rbase + m;

  size_t ir;
  if (GATHER) ir = (size_t)bidx[r] * ADJ_ + nidx[r];
  else        ir = (size_t)r;

  short8v af[4];
  if (ABF16) {
    const unsigned short* arow = (const unsigned short*)in + ir * DV;
#pragma unroll
    for (int kc = 0; kc < 4; kc++)
      af[kc] = *(const short8v*)(arow + kc * 32 + q * 8);
  } else {
    const float* arow = (const float*)in + ir * DV;
#pragma unroll
    for (int kc = 0; kc < 4; kc++) {
      const float4* p = (const float4*)(arow + kc * 32 + q * 8);
      float4 f0 = p[0], f1 = p[1];
      union { short8v s; unsigned int u[4]; } t;
      t.u[0] = pack_bf2(f0.x, f0.y);
      t.u[1] = pack_bf2(f0.z, f0.w);
      t.u[2] = pack_bf2(f1.x, f1.y);
      t.u[3] = pack_bf2(f1.z, f1.w);
      af[kc] = t.s;
    }
  }

  float4v acc[8];
#pragma unroll
  for (int nb = 0; nb < 8; nb++) acc[nb] = (float4v){0.f, 0.f, 0.f, 0.f};
#pragma unroll
  for (int nb = 0; nb < 8; nb++)
#pragma unroll
    for (int kc = 0; kc < 4; kc++) {
      short8v bf = *(const short8v*)(Bs + (((nb * 4 + kc) * 64 + lane) << 3));
      acc[nb] = __builtin_amdgcn_mfma_f32_16x16x32_bf16(af[kc], bf, acc[nb], 0, 0, 0);
    }

#pragma unroll
  for (int nb = 0; nb < 8; nb++) {
    float bvn = HASBIAS ? bias[nb * 16 + m] : 0.f;
    int col = nb * 16 + m;
#pragma unroll
    for (int i = 0; i < 4; i++) {
      int row = rbase + q * 4 + i;
      float v = acc[nb][i] + bvn;
      if (OUTBF16) ((unsigned short*)out_)[(size_t)row * DV + col] = f2bf(v);
      else         ((float*)out_)[(size_t)row * DV + col] = v;
    }
  }
}

// ---------------- K1: fused fill + gemm1 + branch0 ----------------
// Period-16 block pattern: rem 0..7 -> fill (range=rem == blockIdx%8 for XCD
// L2 locality), rem 8..15 -> o = g*8+rem-8: o<1000 gemm1 tile, o<1500 br0 tile.
__global__ __launch_bounds__(256)
void k1_fused(const int* __restrict__ ei, int* __restrict__ counts,
              unsigned short* __restrict__ bucket,
              const float* __restrict__ x1, const float* __restrict__ W1,
              unsigned int* __restrict__ t_bf,
              const float* __restrict__ x0, const float* __restrict__ Wfi,
              const float* __restrict__ bfi, float* __restrict__ out0,
              const int* __restrict__ b0, const int* __restrict__ n0i) {
  __shared__ unsigned short Bs[16384];   // 32 KB
  int g = blockIdx.x >> 4, rem = blockIdx.x & 15;
  if (rem < 8) { fill_part(ei, counts, bucket, g, rem); return; }
  int o = g * 8 + rem - 8;
  if (o < 1000)
    gemm_tile<false, false, true, false>(x1, W1, nullptr, t_bf, o, nullptr, nullptr, Bs);
  else if (o < 1500)
    gemm_tile<true, false, false, true>(x0, Wfi, bfi, out0, o - 1000, b0, n0i, Bs);
}

// ---------------- standalone GEMM ----------------
template<bool GATHER, bool ABF16, bool OUTBF16, bool HASBIAS>
__global__ __launch_bounds__(256)
void gemm_k(const void* __restrict__ in, const float* __restrict__ W,
            const float* __restrict__ bias, void* __restrict__ out_,
            const int* __restrict__ bidx, const int* __restrict__ nidx) {
  __shared__ unsigned short Bs[16384];
  gemm_tile<GATHER, ABF16, OUTBF16, HASBIAS>(in, W, bias, out_, blockIdx.x, bidx, nidx, Bs);
}

// ---------------- aggregation: one wave per row ----------------
// SEL=false: row w = node id (w<N_). SEL=true: row w = output slot, node from
// (bidx,nidx) (w<M_). out row = bias + sum of x[src,:], bf16 or f32.
template<bool OUTBF16, bool SEL>
__global__ __launch_bounds__(256)
void aggregate_k(const unsigned int* __restrict__ x,   // bf16x2 rows [N,64]
                 const int* __restrict__ counts,
                 const unsigned short* __restrict__ bucket,
                 const float* __restrict__ bias, void* __restrict__ out_,
                 const int* __restrict__ bidx, const int* __restrict__ nidx) {
  int w    = (blockIdx.x * 256 + threadIdx.x) >> 6;
  int lane = threadIdx.x & 63;
  int node = SEL ? (bidx[w] * ADJ_ + nidx[w]) : w;
  int cnt = counts[node]; cnt = min(cnt, CAP);
  int mysrc = (int)bucket[node * CAP + lane];
  float2 bv = ((const float2*)bias)[lane];
  float2 acc; acc.x = bv.x; acc.y = bv.y;

  int d = 0;
  for (; d + 4 <= cnt; d += 4) {
    int s0 = __shfl(mysrc, d, 64);
    int s1 = __shfl(mysrc, d + 1, 64);
    int s2 = __shfl(mysrc, d + 2, 64);
    int s3 = __shfl(mysrc, d + 3, 64);
    unsigned int u0 = x[(size_t)s0 * 64 + lane];
    unsigned int u1 = x[(size_t)s1 * 64 + lane];
    unsigned int u2 = x[(size_t)s2 * 64 + lane];
    unsigned int u3 = x[(size_t)s3 * 64 + lane];
    acc.x += (u2f(u0 << 16) + u2f(u1 << 16)) + (u2f(u2 << 16) + u2f(u3 << 16));
    acc.y += (u2f(u0 & 0xffff0000u) + u2f(u1 & 0xffff0000u))
           + (u2f(u2 & 0xffff0000u) + u2f(u3 & 0xffff0000u));
  }
  for (; d < cnt; d++) {
    int s = __shfl(mysrc, d, 64);
    unsigned int u = x[(size_t)s * 64 + lane];
    acc.x += u2f(u << 16);
    acc.y += u2f(u & 0xffff0000u);
  }
  if (OUTBF16) ((unsigned int*)out_)[(size_t)w * 64 + lane] = pack_bf2(acc.x, acc.y);
  else         ((float2*)out_)[(size_t)w * 64 + lane] = acc;
}

extern "C" void kernel_launch(void* const* d_in, const int* in_sizes, int n_in,
                              void* d_out, int out_size, void* d_ws, size_t ws_size,
                              hipStream_t stream) {
  const float* x0  = (const float*)d_in[0];
  const float* x1  = (const float*)d_in[1];
  const int*   ei  = (const int*)  d_in[2];
  const int*   b0  = (const int*)  d_in[3];
  const int*   n0i = (const int*)  d_in[4];
  const int*   b1  = (const int*)  d_in[5];
  const int*   n1i = (const int*)  d_in[6];
  const float* W1  = (const float*)d_in[7];
  const float* bb1 = (const float*)d_in[8];
  const float* W2  = (const float*)d_in[9];
  const float* bb2 = (const float*)d_in[10];
  const float* Wl  = (const float*)d_in[11];
  const float* bl  = (const float*)d_in[12];
  const float* Wfi = (const float*)d_in[13];
  const float* bfi = (const float*)d_in[14];
  float* out = (float*)d_out;

  // ws: t_bf 16MB | h_bf 16MB | sel_bf 8MB | counts 256KB | bucket 8MB
  unsigned int*   t_bf   = (unsigned int*)d_ws;
  unsigned int*   h_bf   = t_bf + (size_t)N_ * 64;
  unsigned int*   sel_bf = h_bf + (size_t)N_ * 64;
  int*            counts = (int*)(sel_bf + (size_t)M_ * 64);
  unsigned short* bucket = (unsigned short*)(counts + N_);

  hipMemsetAsync(counts, 0, N_ * sizeof(int), stream);

  // K1: fill_buckets ∪ t1=x1@W1 ∪ out0=gather(x0)@Wfi+bfi
  k1_fused<<<512 * 16, 256, 0, stream>>>(ei, counts, bucket, x1, W1, t_bf,
                                         x0, Wfi, bfi, out, b0, n0i);

  // h1 = A@t1 + b1  (bf16 out)
  aggregate_k<true, false><<<N_ / 4, 256, 0, stream>>>(t_bf, counts, bucket, bb1,
                                                       h_bf, nullptr, nullptr);
  // t2 = h1@W2  (bf16 out)
  gemm_k<false, true, true, false><<<N_ / 64, 256, 0, stream>>>(h_bf, W2, nullptr,
                                                                t_bf, nullptr, nullptr);
  // sel[m] = b2 + sum_{src in bucket(node(m))} t2[src]  (bf16 out)
  aggregate_k<true, true><<<M_ / 4, 256, 0, stream>>>(t_bf, counts, bucket, bb2,
                                                      sel_bf, b1, n1i);
  // out1 = sel@Wl + bl  (f32 out)
  gemm_k<false, true, false, true><<<M_ / 64, 256, 0, stream>>>(sel_bf, Wl, bl,
                                                                out + (size_t)M_ * DV,
                                                                nullptr, nullptr);
}